// Round 8
// baseline (265.342 us; speedup 1.0000x reference)
//
#include <hip/hip_runtime.h>

typedef __attribute__((ext_vector_type(8))) short short8;
typedef __attribute__((ext_vector_type(8))) unsigned short ushort8;
typedef __attribute__((ext_vector_type(4))) float f32x4;

__device__ __forceinline__ float bf2f(unsigned short u) {
  union { unsigned int u; float f; } c; c.u = ((unsigned int)u) << 16; return c.f;
}
__device__ __forceinline__ unsigned short f2bf(float f) {
  union { float f; unsigned int u; } c; c.f = f;
  unsigned int x = c.u;
  return (unsigned short)((x + 0x7FFFu + ((x >> 16) & 1u)) >> 16);
}

#define GLD_LDS16(g, l)                                                        \
  __builtin_amdgcn_global_load_lds(                                            \
      (const __attribute__((address_space(1))) void*)(g),                      \
      (__attribute__((address_space(3))) void*)(l), 16, 0, 0)

// --------------------------------------------------- fused prep:
// [0,4096): cast X fp32 -> bf16
// [4096,4864): transpose+cast W[1024][3072] -> Wt[3072][1024] bf16
// [4864,8960): zero d_out (needed by out_gemm's split-K atomicAdd)
// 8960: zero Lrow
__global__ __launch_bounds__(256) void prep_kernel(
    const float* __restrict__ X, unsigned short* __restrict__ Xb,
    const float* __restrict__ W, unsigned short* __restrict__ Wt,
    float* __restrict__ out, float* __restrict__ Lrow) {
  const int t = threadIdx.x;
  if (blockIdx.x < 4096) {
    long i = ((long)blockIdx.x * 256 + t) * 8;
    float4 a = *(const float4*)(X + i);
    float4 b = *(const float4*)(X + i + 4);
    ushort8 o;
    o[0] = f2bf(a.x); o[1] = f2bf(a.y); o[2] = f2bf(a.z); o[3] = f2bf(a.w);
    o[4] = f2bf(b.x); o[5] = f2bf(b.y); o[6] = f2bf(b.z); o[7] = f2bf(b.w);
    *(ushort8*)(Xb + i) = o;
  } else if (blockIdx.x < 4864) {
    const int bid = blockIdx.x - 4096;          // 768 blocks = 48 x 16
    const int f0 = (bid % 48) * 64;
    const int e0 = (bid / 48) * 64;
    __shared__ unsigned short tile[64][65];
    const int cg = (t & 15) * 4;
    const int r = t >> 4;
#pragma unroll
    for (int i = 0; i < 4; ++i) {
      int e = r + i * 16;
      float4 v = *(const float4*)(W + (long)(e0 + e) * 3072 + f0 + cg);
      tile[e][cg + 0] = f2bf(v.x);
      tile[e][cg + 1] = f2bf(v.y);
      tile[e][cg + 2] = f2bf(v.z);
      tile[e][cg + 3] = f2bf(v.w);
    }
    __syncthreads();
#pragma unroll
    for (int i = 0; i < 4; ++i) {
      int f = (t >> 4) + i * 16;
      int e = (t & 15) * 4;
      ushort4 o;
      o.x = tile[e + 0][f];
      o.y = tile[e + 1][f];
      o.z = tile[e + 2][f];
      o.w = tile[e + 3][f];
      *(ushort4*)(Wt + (long)(f0 + f) * 1024 + e0 + e) = o;
    }
  } else if (blockIdx.x < 8960) {
    long base = (long)(blockIdx.x - 4864) * 2048 + t * 8;  // 4096 blocks x 2048 floats
    float4 z = {0.f, 0.f, 0.f, 0.f};
    *(float4*)(out + base) = z;
    *(float4*)(out + base + 4) = z;
  } else {
    float4 z = {0.f, 0.f, 0.f, 0.f};
#pragma unroll
    for (int j = 0; j < 8; ++j) *(float4*)(Lrow + (j * 256 + t) * 4) = z;
  }
}

// ---------------------------------------------------------------- GEMM C = A * B^T
// R5-verified m97 structure: 128x128 tile, BK=64, global_load_lds width-16,
// XOR-swizzled LDS, 16x16x32 MFMA, (256,2) launch bounds.
// MODE 0 (qkv): bx<16 -> bf16 C to QK; bx>=16 -> transposed bf16 to Vt (LDS re-tile,
//               ushort4-packed writes).
// MODE 1 (score): bf16 exp(acc*alpha) + row-sum atomicAdd into Lrow.
// MODE 2 (out, split-K x2): blockIdx.z = batch*2 + ksplit; fp32 atomicAdd of
//               acc/Lrow[row] onto pre-zeroed d_out.
template <int MODE>
__device__ __forceinline__ void gemm_body(
    const unsigned short* __restrict__ A, const unsigned short* __restrict__ B,
    void* __restrict__ Cv, int K, int lda, int ldb, int ldc,
    long sA, long sB, long sC, float alpha, float* __restrict__ Lrow,
    unsigned short* __restrict__ Vt) {
  constexpr int BM = 128, BN = 128, BK = 64;
  __shared__ __align__(16) unsigned short smem[BM * BK + BN * BK];  // As | Bs, 32 KB
  unsigned short* As = smem;
  unsigned short* Bs = smem + BM * BK;

  const int t = threadIdx.x;
  const int lane = t & 63;
  const int wave = t >> 6;
  const int quad = lane >> 4;
  const int mrow = lane & 15;
  const int wm = wave >> 1, wn = wave & 1;

  const int bx = blockIdx.x, by = blockIdx.y;
  const int rowA0 = by * BM;
  const int rowB0 = bx * BN;
  int b, kbase;
  if constexpr (MODE == 2) {
    b = blockIdx.z >> 1;
    kbase = (blockIdx.z & 1) * K;
  } else {
    b = blockIdx.z;
    kbase = 0;
  }
  const unsigned short* Ab = A + (long)b * sA + kbase;
  const unsigned short* Bb = B + (long)b * sB + kbase;

  f32x4 acc[4][4];
#pragma unroll
  for (int i = 0; i < 4; ++i)
#pragma unroll
    for (int j = 0; j < 4; ++j) {
      f32x4 z = {0.f, 0.f, 0.f, 0.f};
      acc[i][j] = z;
    }

  const int rbase = wave * 32 + (lane >> 3);
  const int c2 = lane & 7;

  for (int kt = 0; kt < K; kt += BK) {
#pragma unroll
    for (int j = 0; j < 4; ++j) {
      int r = rbase + j * 8;
      int c = c2 ^ (r & 7);
      GLD_LDS16(Ab + (long)(rowA0 + r) * lda + kt + c * 8, As + (wave * 4 + j) * 512);
      GLD_LDS16(Bb + (long)(rowB0 + r) * ldb + kt + c * 8, Bs + (wave * 4 + j) * 512);
    }
    __syncthreads();
#pragma unroll
    for (int ks = 0; ks < 2; ++ks) {
      short8 af[4], bfr[4];
#pragma unroll
      for (int i = 0; i < 4; ++i) {
        int rA = wm * 64 + i * 16 + mrow;
        int cc = ks * 4 + quad;
        af[i] = *(const short8*)(As + (rA * 8 + (cc ^ (rA & 7))) * 8);
        int rB = wn * 64 + i * 16 + mrow;
        bfr[i] = *(const short8*)(Bs + (rB * 8 + (cc ^ (rB & 7))) * 8);
      }
#pragma unroll
      for (int mt = 0; mt < 4; ++mt)
#pragma unroll
        for (int nt = 0; nt < 4; ++nt)
          acc[mt][nt] = __builtin_amdgcn_mfma_f32_16x16x32_bf16(
              af[mt], bfr[nt], acc[mt][nt], 0, 0, 0);
    }
    __syncthreads();
  }

  // epilogue — C/D layout (m89-verified): col = lane&15, row = quad*4 + reg
  const int m_base = rowA0 + wm * 64;
  const int n_base = rowB0 + wn * 64;
  const long cb = (long)b * sC;

  if constexpr (MODE == 0) {
    if (bx < 16) {
      // Q/K columns: plain bf16 write into QK
#pragma unroll
      for (int mt = 0; mt < 4; ++mt)
#pragma unroll
        for (int nt = 0; nt < 4; ++nt)
#pragma unroll
          for (int i = 0; i < 4; ++i) {
            int row = m_base + mt * 16 + quad * 4 + i;
            int col = n_base + nt * 16 + mrow;
            ((unsigned short*)Cv)[cb + (long)row * ldc + col] = f2bf(acc[mt][nt][i]);
          }
    } else {
      // V columns: transpose via LDS (smem = full 128x128 bf16 tile), write Vt.
      // swz(x) = ((x&7)<<4) ^ (((x>>3)&3)<<3) — bits >=3 only, so 4-aligned
      // ushort4 writes and 8-aligned ushort8 reads stay contiguous.
#pragma unroll
      for (int mt = 0; mt < 4; ++mt)
#pragma unroll
        for (int nt = 0; nt < 4; ++nt) {
          int r4 = wm * 64 + mt * 16 + quad * 4;         // 4-aligned tile-local s
          int cL = wn * 64 + nt * 16 + mrow;             // tile-local e
          int swz = ((cL & 7) << 4) ^ (((cL >> 3) & 3) << 3);
          ushort4 pk;
          pk.x = f2bf(acc[mt][nt][0]);
          pk.y = f2bf(acc[mt][nt][1]);
          pk.z = f2bf(acc[mt][nt][2]);
          pk.w = f2bf(acc[mt][nt][3]);
          *(ushort4*)(smem + cL * 128 + (r4 ^ swz)) = pk;
        }
      __syncthreads();
      const int batch = by >> 4;
      const int s_base = (by & 15) * 128;
      const int e_base = (bx - 16) * 128;
      unsigned short* VtB = Vt + (long)batch * 1024 * 2048;
#pragma unroll
      for (int rnd = 0; rnd < 8; ++rnd) {
        int e = (t >> 4) + rnd * 16;
        int s = (t & 15) * 8;
        int swz = ((e & 7) << 4) ^ (((e >> 3) & 3) << 3);
        ushort8 v = *(const ushort8*)(smem + e * 128 + (s ^ swz));
        *(ushort8*)(VtB + (long)(e_base + e) * 2048 + s_base + s) = v;
      }
    }
  } else if constexpr (MODE == 1) {
    // E = exp(acc*alpha), store bf16; accumulate row sums -> Lrow
    float p[4][4];
#pragma unroll
    for (int mt = 0; mt < 4; ++mt)
#pragma unroll
      for (int i = 0; i < 4; ++i) p[mt][i] = 0.f;
#pragma unroll
    for (int mt = 0; mt < 4; ++mt)
#pragma unroll
      for (int nt = 0; nt < 4; ++nt)
#pragma unroll
        for (int i = 0; i < 4; ++i) {
          int row = m_base + mt * 16 + quad * 4 + i;
          int col = n_base + nt * 16 + mrow;
          float e = __expf(acc[mt][nt][i] * alpha);
          ((unsigned short*)Cv)[cb + (long)row * ldc + col] = f2bf(e);
          p[mt][i] += e;
        }
#pragma unroll
    for (int off = 1; off < 16; off <<= 1)
#pragma unroll
      for (int mt = 0; mt < 4; ++mt)
#pragma unroll
        for (int i = 0; i < 4; ++i)
          p[mt][i] += __shfl_xor(p[mt][i], off, 64);
    if (mrow == 0) {
#pragma unroll
      for (int mt = 0; mt < 4; ++mt)
#pragma unroll
        for (int i = 0; i < 4; ++i) {
          int row = m_base + mt * 16 + quad * 4 + i;
          atomicAdd(&Lrow[b * 2048 + row], p[mt][i]);
        }
    }
  } else {
    // split-K partial: atomicAdd acc/L onto pre-zeroed fp32 out
#pragma unroll
    for (int mt = 0; mt < 4; ++mt)
#pragma unroll
      for (int i = 0; i < 4; ++i) {
        int row = m_base + mt * 16 + quad * 4 + i;
        float inv = 1.0f / Lrow[b * 2048 + row];
#pragma unroll
        for (int nt = 0; nt < 4; ++nt) {
          int col = n_base + nt * 16 + mrow;
          atomicAdd((float*)Cv + cb + (long)row * ldc + col, acc[mt][nt][i] * inv);
        }
      }
  }
}

// distinct names so rocprof separates the three GEMMs
__global__ __launch_bounds__(256, 2) void qkv_gemm_kernel(
    const unsigned short* __restrict__ A, const unsigned short* __restrict__ B,
    void* __restrict__ Cv, int K, int lda, int ldb, int ldc,
    long sA, long sB, long sC, float alpha, float* __restrict__ Lrow,
    unsigned short* __restrict__ Vt) {
  gemm_body<0>(A, B, Cv, K, lda, ldb, ldc, sA, sB, sC, alpha, Lrow, Vt);
}
__global__ __launch_bounds__(256, 2) void score_gemm_kernel(
    const unsigned short* __restrict__ A, const unsigned short* __restrict__ B,
    void* __restrict__ Cv, int K, int lda, int ldb, int ldc,
    long sA, long sB, long sC, float alpha, float* __restrict__ Lrow,
    unsigned short* __restrict__ Vt) {
  gemm_body<1>(A, B, Cv, K, lda, ldb, ldc, sA, sB, sC, alpha, Lrow, Vt);
}
__global__ __launch_bounds__(256, 2) void out_gemm_kernel(
    const unsigned short* __restrict__ A, const unsigned short* __restrict__ B,
    void* __restrict__ Cv, int K, int lda, int ldb, int ldc,
    long sA, long sB, long sC, float alpha, float* __restrict__ Lrow,
    unsigned short* __restrict__ Vt) {
  gemm_body<2>(A, B, Cv, K, lda, ldb, ldc, sA, sB, sC, alpha, Lrow, Vt);
}

// ---------------------------------------------------------------- launch
extern "C" void kernel_launch(void* const* d_in, const int* in_sizes, int n_in,
                              void* d_out, int out_size, void* d_ws, size_t ws_size,
                              hipStream_t stream) {
  const float* X = (const float*)d_in[0];  // [4,2048,1024] fp32
  const float* W = (const float*)d_in[1];  // [1024,3072] fp32
  float* out = (float*)d_out;              // [4,2048,1024] fp32

  char* ws = (char*)d_ws;
  unsigned short* Xb  = (unsigned short*)(ws);                 // 8192x1024 bf16   (16 MiB)
  unsigned short* Wtb = (unsigned short*)(ws + 16777216);      // 3072x1024 bf16   ( 6 MiB)
  unsigned short* QK  = (unsigned short*)(ws + 23068672);      // 8192x2048 bf16   (32 MiB)
  unsigned short* Vt  = (unsigned short*)(ws + 56623104);      // 4x1024x2048 bf16 (16 MiB)
  unsigned short* Sb  = (unsigned short*)(ws + 73400320);      // 4x2048x2048 bf16 (32 MiB)
  float* Lrow         = (float*)(ws + 106954752);              // 4x2048 fp32      (32 KiB)

  // 1. prep: cast X, transpose W, zero d_out + Lrow
  prep_kernel<<<8961, 256, 0, stream>>>(X, Xb, W, Wtb, out, Lrow);

  // 2. [Q|K] = Xb @ Wtb^T  (bx<16 -> QK, ldc=2048); V -> Vt transposed (bx>=16)
  qkv_gemm_kernel<<<dim3(24, 64, 1), 256, 0, stream>>>(
      Xb, Wtb, QK, 1024, 1024, 1024, 2048, 0L, 0L, 0L, 1.0f, nullptr, Vt);

  // 3. E = exp(Q @ K^T / 32) per batch [2048 x 2048], K=1024; row sums -> Lrow
  score_gemm_kernel<<<dim3(16, 16, 4), 256, 0, stream>>>(
      QK, QK + 1024, Sb, 1024, 2048, 2048, 2048,
      (long)2048 * 2048, (long)2048 * 2048, (long)2048 * 2048, 0.03125f, Lrow, nullptr);

  // 4. O += (E_half @ Vt_half^T) / L  — split-K x2, z = batch*2 + ksplit
  out_gemm_kernel<<<dim3(8, 16, 8), 256, 0, stream>>>(
      Sb, Vt, out, 1024, 2048, 2048, 1024,
      (long)2048 * 2048, (long)1024 * 2048, (long)2048 * 1024, 1.0f, Lrow, nullptr);
}

// Round 9
// 227.827 us; speedup vs baseline: 1.1647x; 1.1647x over previous
//
#include <hip/hip_runtime.h>

typedef __attribute__((ext_vector_type(8))) short short8;
typedef __attribute__((ext_vector_type(8))) unsigned short ushort8;
typedef __attribute__((ext_vector_type(4))) float f32x4;

__device__ __forceinline__ float bf2f(unsigned short u) {
  union { unsigned int u; float f; } c; c.u = ((unsigned int)u) << 16; return c.f;
}
__device__ __forceinline__ unsigned short f2bf(float f) {
  union { float f; unsigned int u; } c; c.f = f;
  unsigned int x = c.u;
  return (unsigned short)((x + 0x7FFFu + ((x >> 16) & 1u)) >> 16);
}

#define GLD_LDS16(g, l)                                                        \
  __builtin_amdgcn_global_load_lds(                                            \
      (const __attribute__((address_space(1))) void*)(g),                      \
      (__attribute__((address_space(3))) void*)(l), 16, 0, 0)

// --------------------------------------------------- fused prep:
// [0,4096): cast X fp32 -> bf16
// [4096,4864): transpose+cast W[1024][3072] -> Wt[3072][1024] bf16
// 4864: zero Lrow
__global__ __launch_bounds__(256) void prep_kernel(
    const float* __restrict__ X, unsigned short* __restrict__ Xb,
    const float* __restrict__ W, unsigned short* __restrict__ Wt,
    float* __restrict__ Lrow) {
  const int t = threadIdx.x;
  if (blockIdx.x < 4096) {
    long i = ((long)blockIdx.x * 256 + t) * 8;
    float4 a = *(const float4*)(X + i);
    float4 b = *(const float4*)(X + i + 4);
    ushort8 o;
    o[0] = f2bf(a.x); o[1] = f2bf(a.y); o[2] = f2bf(a.z); o[3] = f2bf(a.w);
    o[4] = f2bf(b.x); o[5] = f2bf(b.y); o[6] = f2bf(b.z); o[7] = f2bf(b.w);
    *(ushort8*)(Xb + i) = o;
  } else if (blockIdx.x < 4864) {
    const int bid = blockIdx.x - 4096;          // 768 blocks = 48 x 16
    const int f0 = (bid % 48) * 64;
    const int e0 = (bid / 48) * 64;
    __shared__ unsigned short tile[64][65];
    const int cg = (t & 15) * 4;
    const int r = t >> 4;
#pragma unroll
    for (int i = 0; i < 4; ++i) {
      int e = r + i * 16;
      float4 v = *(const float4*)(W + (long)(e0 + e) * 3072 + f0 + cg);
      tile[e][cg + 0] = f2bf(v.x);
      tile[e][cg + 1] = f2bf(v.y);
      tile[e][cg + 2] = f2bf(v.z);
      tile[e][cg + 3] = f2bf(v.w);
    }
    __syncthreads();
#pragma unroll
    for (int i = 0; i < 4; ++i) {
      int f = (t >> 4) + i * 16;
      int e = (t & 15) * 4;
      ushort4 o;
      o.x = tile[e + 0][f];
      o.y = tile[e + 1][f];
      o.z = tile[e + 2][f];
      o.w = tile[e + 3][f];
      *(ushort4*)(Wt + (long)(f0 + f) * 1024 + e0 + e) = o;
    }
  } else {
    float4 z = {0.f, 0.f, 0.f, 0.f};
#pragma unroll
    for (int j = 0; j < 8; ++j) *(float4*)(Lrow + (j * 256 + t) * 4) = z;
  }
}

// ---------------------------------------------------------------- GEMM C = A * B^T
// R5-verified m97 structure: 128x128 tile, BK=64, global_load_lds width-16,
// XOR-swizzled LDS, 16x16x32 MFMA, (256,2) launch bounds.
// MODE 0 (qkv): bx<16 -> bf16 C to QK; bx>=16 -> transposed bf16 to Vt (LDS re-tile,
//               ushort4-packed writes).
// MODE 1 (score): bf16 exp(acc*alpha) + row-sum atomicAdd into Lrow.
// MODE 2 (out): direct fp32 store of acc/Lrow[row]. (R8's split-K atomicAdd
//               regressed 58->83 us: 8.4M RMWs, FETCH +70 MB; reverted.)
template <int MODE>
__device__ __forceinline__ void gemm_body(
    const unsigned short* __restrict__ A, const unsigned short* __restrict__ B,
    void* __restrict__ Cv, int K, int lda, int ldb, int ldc,
    long sA, long sB, long sC, float alpha, float* __restrict__ Lrow,
    unsigned short* __restrict__ Vt) {
  constexpr int BM = 128, BN = 128, BK = 64;
  __shared__ __align__(16) unsigned short smem[BM * BK + BN * BK];  // As | Bs, 32 KB
  unsigned short* As = smem;
  unsigned short* Bs = smem + BM * BK;

  const int t = threadIdx.x;
  const int lane = t & 63;
  const int wave = t >> 6;
  const int quad = lane >> 4;
  const int mrow = lane & 15;
  const int wm = wave >> 1, wn = wave & 1;

  const int bx = blockIdx.x, by = blockIdx.y;
  const int rowA0 = by * BM;
  const int rowB0 = bx * BN;
  const int b = blockIdx.z;
  const unsigned short* Ab = A + (long)b * sA;
  const unsigned short* Bb = B + (long)b * sB;

  f32x4 acc[4][4];
#pragma unroll
  for (int i = 0; i < 4; ++i)
#pragma unroll
    for (int j = 0; j < 4; ++j) {
      f32x4 z = {0.f, 0.f, 0.f, 0.f};
      acc[i][j] = z;
    }

  const int rbase = wave * 32 + (lane >> 3);
  const int c2 = lane & 7;

  for (int kt = 0; kt < K; kt += BK) {
#pragma unroll
    for (int j = 0; j < 4; ++j) {
      int r = rbase + j * 8;
      int c = c2 ^ (r & 7);
      GLD_LDS16(Ab + (long)(rowA0 + r) * lda + kt + c * 8, As + (wave * 4 + j) * 512);
      GLD_LDS16(Bb + (long)(rowB0 + r) * ldb + kt + c * 8, Bs + (wave * 4 + j) * 512);
    }
    __syncthreads();
#pragma unroll
    for (int ks = 0; ks < 2; ++ks) {
      short8 af[4], bfr[4];
#pragma unroll
      for (int i = 0; i < 4; ++i) {
        int rA = wm * 64 + i * 16 + mrow;
        int cc = ks * 4 + quad;
        af[i] = *(const short8*)(As + (rA * 8 + (cc ^ (rA & 7))) * 8);
        int rB = wn * 64 + i * 16 + mrow;
        bfr[i] = *(const short8*)(Bs + (rB * 8 + (cc ^ (rB & 7))) * 8);
      }
#pragma unroll
      for (int mt = 0; mt < 4; ++mt)
#pragma unroll
        for (int nt = 0; nt < 4; ++nt)
          acc[mt][nt] = __builtin_amdgcn_mfma_f32_16x16x32_bf16(
              af[mt], bfr[nt], acc[mt][nt], 0, 0, 0);
    }
    __syncthreads();
  }

  // epilogue — C/D layout (m89-verified): col = lane&15, row = quad*4 + reg
  const int m_base = rowA0 + wm * 64;
  const int n_base = rowB0 + wn * 64;
  const long cb = (long)b * sC;

  if constexpr (MODE == 0) {
    if (bx < 16) {
      // Q/K columns: plain bf16 write into QK
#pragma unroll
      for (int mt = 0; mt < 4; ++mt)
#pragma unroll
        for (int nt = 0; nt < 4; ++nt)
#pragma unroll
          for (int i = 0; i < 4; ++i) {
            int row = m_base + mt * 16 + quad * 4 + i;
            int col = n_base + nt * 16 + mrow;
            ((unsigned short*)Cv)[cb + (long)row * ldc + col] = f2bf(acc[mt][nt][i]);
          }
    } else {
      // V columns: transpose via LDS (smem = full 128x128 bf16 tile), write Vt.
      // swz(x) = ((x&7)<<4) ^ (((x>>3)&3)<<3) — bits >=3 only, so 4-aligned
      // ushort4 writes and 8-aligned ushort8 reads stay contiguous.
#pragma unroll
      for (int mt = 0; mt < 4; ++mt)
#pragma unroll
        for (int nt = 0; nt < 4; ++nt) {
          int r4 = wm * 64 + mt * 16 + quad * 4;         // 4-aligned tile-local s
          int cL = wn * 64 + nt * 16 + mrow;             // tile-local e
          int swz = ((cL & 7) << 4) ^ (((cL >> 3) & 3) << 3);
          ushort4 pk;
          pk.x = f2bf(acc[mt][nt][0]);
          pk.y = f2bf(acc[mt][nt][1]);
          pk.z = f2bf(acc[mt][nt][2]);
          pk.w = f2bf(acc[mt][nt][3]);
          *(ushort4*)(smem + cL * 128 + (r4 ^ swz)) = pk;
        }
      __syncthreads();
      const int batch = by >> 4;
      const int s_base = (by & 15) * 128;
      const int e_base = (bx - 16) * 128;
      unsigned short* VtB = Vt + (long)batch * 1024 * 2048;
#pragma unroll
      for (int rnd = 0; rnd < 8; ++rnd) {
        int e = (t >> 4) + rnd * 16;
        int s = (t & 15) * 8;
        int swz = ((e & 7) << 4) ^ (((e >> 3) & 3) << 3);
        ushort8 v = *(const ushort8*)(smem + e * 128 + (s ^ swz));
        *(ushort8*)(VtB + (long)(e_base + e) * 2048 + s_base + s) = v;
      }
    }
  } else if constexpr (MODE == 1) {
    // E = exp(acc*alpha), store bf16; accumulate row sums -> Lrow
    float p[4][4];
#pragma unroll
    for (int mt = 0; mt < 4; ++mt)
#pragma unroll
      for (int i = 0; i < 4; ++i) p[mt][i] = 0.f;
#pragma unroll
    for (int mt = 0; mt < 4; ++mt)
#pragma unroll
      for (int nt = 0; nt < 4; ++nt)
#pragma unroll
        for (int i = 0; i < 4; ++i) {
          int row = m_base + mt * 16 + quad * 4 + i;
          int col = n_base + nt * 16 + mrow;
          float e = __expf(acc[mt][nt][i] * alpha);
          ((unsigned short*)Cv)[cb + (long)row * ldc + col] = f2bf(e);
          p[mt][i] += e;
        }
#pragma unroll
    for (int off = 1; off < 16; off <<= 1)
#pragma unroll
      for (int mt = 0; mt < 4; ++mt)
#pragma unroll
        for (int i = 0; i < 4; ++i)
          p[mt][i] += __shfl_xor(p[mt][i], off, 64);
    if (mrow == 0) {
#pragma unroll
      for (int mt = 0; mt < 4; ++mt)
#pragma unroll
        for (int i = 0; i < 4; ++i) {
          int row = m_base + mt * 16 + quad * 4 + i;
          atomicAdd(&Lrow[b * 2048 + row], p[mt][i]);
        }
    }
  } else {
    // fp32 out, scaled by 1/Lrow[row]
#pragma unroll
    for (int mt = 0; mt < 4; ++mt)
#pragma unroll
      for (int i = 0; i < 4; ++i) {
        int row = m_base + mt * 16 + quad * 4 + i;
        float inv = 1.0f / Lrow[b * 2048 + row];
#pragma unroll
        for (int nt = 0; nt < 4; ++nt) {
          int col = n_base + nt * 16 + mrow;
          ((float*)Cv)[cb + (long)row * ldc + col] = acc[mt][nt][i] * inv;
        }
      }
  }
}

// distinct names so rocprof separates the three GEMMs
__global__ __launch_bounds__(256, 2) void qkv_gemm_kernel(
    const unsigned short* __restrict__ A, const unsigned short* __restrict__ B,
    void* __restrict__ Cv, int K, int lda, int ldb, int ldc,
    long sA, long sB, long sC, float alpha, float* __restrict__ Lrow,
    unsigned short* __restrict__ Vt) {
  gemm_body<0>(A, B, Cv, K, lda, ldb, ldc, sA, sB, sC, alpha, Lrow, Vt);
}
__global__ __launch_bounds__(256, 2) void score_gemm_kernel(
    const unsigned short* __restrict__ A, const unsigned short* __restrict__ B,
    void* __restrict__ Cv, int K, int lda, int ldb, int ldc,
    long sA, long sB, long sC, float alpha, float* __restrict__ Lrow,
    unsigned short* __restrict__ Vt) {
  gemm_body<1>(A, B, Cv, K, lda, ldb, ldc, sA, sB, sC, alpha, Lrow, Vt);
}
__global__ __launch_bounds__(256, 2) void out_gemm_kernel(
    const unsigned short* __restrict__ A, const unsigned short* __restrict__ B,
    void* __restrict__ Cv, int K, int lda, int ldb, int ldc,
    long sA, long sB, long sC, float alpha, float* __restrict__ Lrow,
    unsigned short* __restrict__ Vt) {
  gemm_body<2>(A, B, Cv, K, lda, ldb, ldc, sA, sB, sC, alpha, Lrow, Vt);
}

// ---------------------------------------------------------------- launch
extern "C" void kernel_launch(void* const* d_in, const int* in_sizes, int n_in,
                              void* d_out, int out_size, void* d_ws, size_t ws_size,
                              hipStream_t stream) {
  const float* X = (const float*)d_in[0];  // [4,2048,1024] fp32
  const float* W = (const float*)d_in[1];  // [1024,3072] fp32
  float* out = (float*)d_out;              // [4,2048,1024] fp32

  char* ws = (char*)d_ws;
  unsigned short* Xb  = (unsigned short*)(ws);                 // 8192x1024 bf16   (16 MiB)
  unsigned short* Wtb = (unsigned short*)(ws + 16777216);      // 3072x1024 bf16   ( 6 MiB)
  unsigned short* QK  = (unsigned short*)(ws + 23068672);      // 8192x2048 bf16   (32 MiB)
  unsigned short* Vt  = (unsigned short*)(ws + 56623104);      // 4x1024x2048 bf16 (16 MiB)
  unsigned short* Sb  = (unsigned short*)(ws + 73400320);      // 4x2048x2048 bf16 (32 MiB)
  float* Lrow         = (float*)(ws + 106954752);              // 4x2048 fp32      (32 KiB)

  // 1. prep: cast X, transpose W, zero Lrow
  prep_kernel<<<4865, 256, 0, stream>>>(X, Xb, W, Wtb, Lrow);

  // 2. [Q|K] = Xb @ Wtb^T  (bx<16 -> QK, ldc=2048); V -> Vt transposed (bx>=16)
  qkv_gemm_kernel<<<dim3(24, 64, 1), 256, 0, stream>>>(
      Xb, Wtb, QK, 1024, 1024, 1024, 2048, 0L, 0L, 0L, 1.0f, nullptr, Vt);

  // 3. E = exp(Q @ K^T / 32) per batch [2048 x 2048], K=1024; row sums -> Lrow
  score_gemm_kernel<<<dim3(16, 16, 4), 256, 0, stream>>>(
      QK, QK + 1024, Sb, 1024, 2048, 2048, 2048,
      (long)2048 * 2048, (long)2048 * 2048, (long)2048 * 2048, 0.03125f, Lrow, nullptr);

  // 4. O = (E @ Vt^T) / L  per batch  [2048 x 1024], K=2048 -> fp32 out
  out_gemm_kernel<<<dim3(8, 16, 4), 256, 0, stream>>>(
      Sb, Vt, out, 2048, 2048, 2048, 1024,
      (long)2048 * 2048, (long)1024 * 2048, (long)2048 * 1024, 1.0f, Lrow, nullptr);
}